// Round 1
// baseline (66.367 us; speedup 1.0000x reference)
//
#include <hip/hip_runtime.h>
#include <math.h>

#define RR      300   // rois per image
#define NCLS    21    // classes incl background
#define NFG     20    // foreground classes
#define KK      21    // output pad size (== num_classes)
#define THREADS 256
#define NMS_THR 0.3f

// Block FMA contraction: t = a*b rounded separately, then + c.
__device__ __forceinline__ float madd_nofma(float a, float b, float c) {
    float t = a * b;
    asm volatile("" : "+v"(t));
    return t + c;
}

// Correctly-rounded float32 exp via double
__device__ __forceinline__ float exp_acc(float x) {
    return (float)exp((double)x);
}

__global__ __launch_bounds__(THREADS)
void nms_per_class_kernel(const float* __restrict__ cls_prob,   // [B,RR,NCLS]
                          const float* __restrict__ rois,       // [B,RR,5]
                          const float* __restrict__ bbox_pred,  // [B,RR,4*NCLS]
                          const float* __restrict__ im_info,    // [B,3]
                          const float* __restrict__ thr,        // [NCLS]
                          float* __restrict__ wsBoxes,          // [B,NFG,RR,4] sorted
                          int*   __restrict__ wsKeep)           // [B,NFG,RR]
{
    const int blk = blockIdx.x;
    const int b  = blk / NFG;
    const int ci = blk % NFG;
    const int c  = ci + 1;          // skip background
    const int tid = threadIdx.x;

    __shared__ float s_sm[RR];      // masked scores (-inf if below threshold)
    __shared__ float s_sbox[RR * 4];// boxes in score-rank order
    __shared__ float s_area[RR];
    __shared__ int   s_keep[RR];
    __shared__ int   s_nvalid;

    if (tid == 0) s_nvalid = 0;
    __syncthreads();

    const float imH = im_info[b * 3 + 0];
    const float imW = im_info[b * 3 + 1];
    const float t   = thr[c];

    // ---- Phase A: masked scores + valid count ----
    int nval_local = 0;
    for (int r = tid; r < RR; r += THREADS) {
        float s = cls_prob[(b * RR + r) * NCLS + c];
        bool valid = s > t;
        s_sm[r] = valid ? s : -INFINITY;
        nval_local += valid ? 1 : 0;
    }
    if (nval_local) atomicAdd(&s_nvalid, nval_local);
    __syncthreads();

    // ---- Phase B: stable rank (== argsort(-sm)) + decode into sorted slot ----
    for (int r = tid; r < RR; r += THREADS) {
        float key = s_sm[r];
        int rank = 0;
        for (int j = 0; j < RR; ++j) {
            float kj = s_sm[j];
            rank += (kj > key || (kj == key && j < r)) ? 1 : 0;
        }
        // decode roi r for class c
        float x1 = rois[(b * RR + r) * 5 + 1];
        float y1 = rois[(b * RR + r) * 5 + 2];
        float x2 = rois[(b * RR + r) * 5 + 3];
        float y2 = rois[(b * RR + r) * 5 + 4];
        float w  = x2 - x1 + 1.0f;
        float h  = y2 - y1 + 1.0f;
        float cx = x1 + 0.5f * w;       // *0.5 exact
        float cy = y1 + 0.5f * h;
        const float* dp = &bbox_pred[((b * RR + r) * NCLS + c) * 4];
        float dx = dp[0] * 0.1f;
        float dy = dp[1] * 0.1f;
        float dw = dp[2] * 0.2f;
        float dh = dp[3] * 0.2f;
        float pcx = madd_nofma(dx, w, cx);
        float pcy = madd_nofma(dy, h, cy);
        float pw  = exp_acc(dw) * w;
        float ph  = exp_acc(dh) * h;
        float bx1 = fminf(fmaxf(pcx - 0.5f * pw, 0.0f), imW - 1.0f);
        float by1 = fminf(fmaxf(pcy - 0.5f * ph, 0.0f), imH - 1.0f);
        float bx2 = fminf(fmaxf(pcx + 0.5f * pw, 0.0f), imW - 1.0f);
        float by2 = fminf(fmaxf(pcy + 0.5f * ph, 0.0f), imH - 1.0f);
        s_sbox[rank * 4 + 0] = bx1;
        s_sbox[rank * 4 + 1] = by1;
        s_sbox[rank * 4 + 2] = bx2;
        s_sbox[rank * 4 + 3] = by2;
        s_area[rank] = (bx2 - bx1 + 1.0f) * (by2 - by1 + 1.0f);
        s_keep[rank] = (key != -INFINITY) ? 1 : 0;
    }
    __syncthreads();

    const int nvalid = s_nvalid;

    // ---- Phase C: greedy NMS; each thread owns up to 2 candidate boxes ----
    const int j0 = tid;
    const int j1 = tid + THREADS;
    const bool h1 = (j1 < RR);
    float a0x1 = s_sbox[j0 * 4 + 0], a0y1 = s_sbox[j0 * 4 + 1];
    float a0x2 = s_sbox[j0 * 4 + 2], a0y2 = s_sbox[j0 * 4 + 3];
    float a0ar = s_area[j0];
    int jj = h1 ? j1 : 0;
    float a1x1 = s_sbox[jj * 4 + 0], a1y1 = s_sbox[jj * 4 + 1];
    float a1x2 = s_sbox[jj * 4 + 2], a1y2 = s_sbox[jj * 4 + 3];
    float a1ar = s_area[jj];

    // prefetch box 0
    float ix1 = s_sbox[0], iy1 = s_sbox[1], ix2 = s_sbox[2], iy2 = s_sbox[3];
    float iar = s_area[0];
    for (int i = 0; i < nvalid; ++i) {
        int ki = s_keep[i];
        int ip = (i + 1 < RR) ? (i + 1) : (RR - 1);
        float nx1 = s_sbox[ip * 4 + 0], ny1 = s_sbox[ip * 4 + 1];
        float nx2 = s_sbox[ip * 4 + 2], ny2 = s_sbox[ip * 4 + 3];
        float nar = s_area[ip];
        if (ki) {
            if (j0 > i) {
                float xx1 = fmaxf(ix1, a0x1), yy1 = fmaxf(iy1, a0y1);
                float xx2 = fminf(ix2, a0x2), yy2 = fminf(iy2, a0y2);
                float inter = fmaxf(xx2 - xx1 + 1.0f, 0.0f) * fmaxf(yy2 - yy1 + 1.0f, 0.0f);
                float iou = inter / (iar + a0ar - inter);
                if (iou > NMS_THR) s_keep[j0] = 0;
            }
            if (h1 && j1 > i) {
                float xx1 = fmaxf(ix1, a1x1), yy1 = fmaxf(iy1, a1y1);
                float xx2 = fminf(ix2, a1x2), yy2 = fminf(iy2, a1y2);
                float inter = fmaxf(xx2 - xx1 + 1.0f, 0.0f) * fmaxf(yy2 - yy1 + 1.0f, 0.0f);
                float iou = inter / (iar + a1ar - inter);
                if (iou > NMS_THR) s_keep[j1] = 0;
            }
        }
        __syncthreads();
        ix1 = nx1; iy1 = ny1; ix2 = nx2; iy2 = ny2; iar = nar;
    }

    // ---- Phase D: write sorted boxes + keep flags to workspace ----
    const int base = (b * NFG + ci) * RR;
    for (int p = tid; p < RR; p += THREADS) {
        wsKeep[base + p] = s_keep[p];
        wsBoxes[(base + p) * 4 + 0] = s_sbox[p * 4 + 0];
        wsBoxes[(base + p) * 4 + 1] = s_sbox[p * 4 + 1];
        wsBoxes[(base + p) * 4 + 2] = s_sbox[p * 4 + 2];
        wsBoxes[(base + p) * 4 + 3] = s_sbox[p * 4 + 3];
    }
}

__global__ __launch_bounds__(THREADS)
void select_topk_kernel(const float* __restrict__ wsBoxes,
                        const int*   __restrict__ wsKeep,
                        float* __restrict__ out,   // [B,KK,5] then [B] counts
                        int B)
{
    const int b = blockIdx.x;
    const int tid = threadIdx.x;
    const int NE = NFG * RR;                       // 6000
    const int CH = (NE + THREADS - 1) / THREADS;   // 24

    __shared__ int s_cnt[THREADS];
    __shared__ int s_off[THREADS + 1];

    const int begin = tid * CH;
    const int end   = (begin + CH < NE) ? (begin + CH) : NE;
    const int* kp = wsKeep + (size_t)b * NE;

    int cnt = 0;
    for (int e = begin; e < end; ++e) cnt += kp[e];
    s_cnt[tid] = cnt;
    __syncthreads();

    if (tid == 0) {
        int acc = 0;
        for (int t2 = 0; t2 < THREADS; ++t2) { s_off[t2] = acc; acc += s_cnt[t2]; }
        s_off[THREADS] = acc;
    }
    __syncthreads();

    const int total = s_off[THREADS];
    const int n = (total < KK) ? total : KK;
    int rank = s_off[tid];
    const float* bp = wsBoxes + (size_t)b * NE * 4;
    float* ob = out + (size_t)b * (KK * 5);

    if (rank < KK) {
        for (int e = begin; e < end && rank < KK; ++e) {
            if (kp[e]) {
                int cls = e / RR + 1;
                ob[rank * 5 + 0] = bp[e * 4 + 0];
                ob[rank * 5 + 1] = bp[e * 4 + 1];
                ob[rank * 5 + 2] = bp[e * 4 + 2];
                ob[rank * 5 + 3] = bp[e * 4 + 3];
                ob[rank * 5 + 4] = (float)cls;
                ++rank;
            }
        }
    }
    // zero-pad rows [n, KK)
    for (int k2 = tid; k2 < KK; k2 += THREADS) {
        if (k2 >= n) {
            ob[k2 * 5 + 0] = 0.0f;
            ob[k2 * 5 + 1] = 0.0f;
            ob[k2 * 5 + 2] = 0.0f;
            ob[k2 * 5 + 3] = 0.0f;
            ob[k2 * 5 + 4] = 0.0f;
        }
    }
    if (tid == 0) out[(size_t)B * KK * 5 + b] = (float)n;  // count as float32
}

extern "C" void kernel_launch(void* const* d_in, const int* in_sizes, int n_in,
                              void* d_out, int out_size, void* d_ws, size_t ws_size,
                              hipStream_t stream)
{
    const float* cls_prob  = (const float*)d_in[0];
    const float* rois      = (const float*)d_in[1];
    const float* bbox_pred = (const float*)d_in[2];
    const float* im_info   = (const float*)d_in[3];
    const float* thr       = (const float*)d_in[4];
    const int B = in_sizes[3] / 3;   // im_info is [B,3]

    float* wsBoxes = (float*)d_ws;
    int*   wsKeep  = (int*)((char*)d_ws + (size_t)B * NFG * RR * 4 * sizeof(float));

    nms_per_class_kernel<<<B * NFG, THREADS, 0, stream>>>(
        cls_prob, rois, bbox_pred, im_info, thr, wsBoxes, wsKeep);
    select_topk_kernel<<<B, THREADS, 0, stream>>>(
        wsBoxes, wsKeep, (float*)d_out, B);
}

// Round 2
// 64.900 us; speedup vs baseline: 1.0226x; 1.0226x over previous
//
#include <hip/hip_runtime.h>
#include <math.h>

#define RR      300   // rois per image
#define NCLS    21    // classes incl background
#define NFG     20    // foreground classes
#define KK      21    // output pad size (== num_classes)
#define THREADS 256
#define NWORDS  10    // ceil(300/32) 32-bit keep words
#define NMS_THR 0.3f

// Block FMA contraction: t = a*b rounded separately, then + c. (bit-exact vs ref, proven R1)
__device__ __forceinline__ float madd_nofma(float a, float b, float c) {
    float t = a * b;
    asm volatile("" : "+v"(t));
    return t + c;
}

// Correctly-rounded float32 exp via double (bit-exact vs ref, proven R1)
__device__ __forceinline__ float exp_acc(float x) {
    return (float)exp((double)x);
}

__global__ __launch_bounds__(THREADS)
void nms_per_class_kernel(const float* __restrict__ cls_prob,   // [B,RR,NCLS]
                          const float* __restrict__ rois,       // [B,RR,5]
                          const float* __restrict__ bbox_pred,  // [B,RR,4*NCLS]
                          const float* __restrict__ im_info,    // [B,3]
                          const float* __restrict__ thr,        // [NCLS]
                          float* __restrict__ wsBoxes,          // [B,NFG,KK,4] compact kept boxes
                          int*   __restrict__ wsCount)          // [B,NFG] full kept count
{
    const int blk = blockIdx.x;
    const int b  = blk / NFG;
    const int ci = blk % NFG;
    const int c  = ci + 1;          // skip background
    const int tid = threadIdx.x;

    __shared__ float s_sm[RR];              // masked scores (-inf if below threshold)
    __shared__ float s_sbox[RR * 4];        // boxes in score-rank order
    __shared__ float s_area[RR];
    __shared__ unsigned int s_sup[RR * NWORDS];  // suppression bitmask rows
    __shared__ unsigned int s_keepw[NWORDS];
    __shared__ int s_nvalid;

    if (tid == 0) s_nvalid = 0;
    __syncthreads();

    const float imH = im_info[b * 3 + 0];
    const float imW = im_info[b * 3 + 1];
    const float t   = thr[c];

    // ---- Phase A: masked scores + valid count ----
    int nval_local = 0;
    for (int r = tid; r < RR; r += THREADS) {
        float s = cls_prob[(b * RR + r) * NCLS + c];
        bool valid = s > t;
        s_sm[r] = valid ? s : -INFINITY;
        nval_local += valid ? 1 : 0;
    }
    if (nval_local) atomicAdd(&s_nvalid, nval_local);
    __syncthreads();

    // ---- Phase B: stable rank (== argsort(-sm)) + decode into sorted slot ----
    for (int r = tid; r < RR; r += THREADS) {
        float key = s_sm[r];
        int rank = 0;
        for (int j = 0; j < RR; ++j) {
            float kj = s_sm[j];
            rank += (kj > key || (kj == key && j < r)) ? 1 : 0;
        }
        // decode roi r for class c (expression forms identical to R1 — bit-exact)
        float x1 = rois[(b * RR + r) * 5 + 1];
        float y1 = rois[(b * RR + r) * 5 + 2];
        float x2 = rois[(b * RR + r) * 5 + 3];
        float y2 = rois[(b * RR + r) * 5 + 4];
        float w  = x2 - x1 + 1.0f;
        float h  = y2 - y1 + 1.0f;
        float cx = x1 + 0.5f * w;
        float cy = y1 + 0.5f * h;
        const float* dp = &bbox_pred[((b * RR + r) * NCLS + c) * 4];
        float dx = dp[0] * 0.1f;
        float dy = dp[1] * 0.1f;
        float dw = dp[2] * 0.2f;
        float dh = dp[3] * 0.2f;
        float pcx = madd_nofma(dx, w, cx);
        float pcy = madd_nofma(dy, h, cy);
        float pw  = exp_acc(dw) * w;
        float ph  = exp_acc(dh) * h;
        float bx1 = fminf(fmaxf(pcx - 0.5f * pw, 0.0f), imW - 1.0f);
        float by1 = fminf(fmaxf(pcy - 0.5f * ph, 0.0f), imH - 1.0f);
        float bx2 = fminf(fmaxf(pcx + 0.5f * pw, 0.0f), imW - 1.0f);
        float by2 = fminf(fmaxf(pcy + 0.5f * ph, 0.0f), imH - 1.0f);
        s_sbox[rank * 4 + 0] = bx1;
        s_sbox[rank * 4 + 1] = by1;
        s_sbox[rank * 4 + 2] = bx2;
        s_sbox[rank * 4 + 3] = by2;
        s_area[rank] = (bx2 - bx1 + 1.0f) * (by2 - by1 + 1.0f);
    }
    __syncthreads();

    const int nv = s_nvalid;

    // ---- Phase C: parallel suppression bit-matrix (no barriers inside) ----
    for (int task = tid; task < RR * NWORDS; task += THREADS) {
        const int i = task / NWORDS;
        const int w = task - i * NWORDS;
        if (i >= nv) continue;                    // row never read by scan
        const int jBase = w << 5;
        unsigned int bits = 0u;
        if (jBase < nv && jBase + 32 > i + 1) {   // word has potential j>i, j<nv
            const float ix1 = s_sbox[i * 4 + 0];
            const float iy1 = s_sbox[i * 4 + 1];
            const float ix2 = s_sbox[i * 4 + 2];
            const float iy2 = s_sbox[i * 4 + 3];
            const float iar = s_area[i];
            #pragma unroll 4
            for (int jj = 0; jj < 32; ++jj) {
                const int j = jBase + jj;
                const int jc = (j < RR) ? j : 0;  // clamp (bits masked below)
                float xx1 = fmaxf(ix1, s_sbox[jc * 4 + 0]);
                float yy1 = fmaxf(iy1, s_sbox[jc * 4 + 1]);
                float xx2 = fminf(ix2, s_sbox[jc * 4 + 2]);
                float yy2 = fminf(iy2, s_sbox[jc * 4 + 3]);
                float inter = fmaxf(xx2 - xx1 + 1.0f, 0.0f) * fmaxf(yy2 - yy1 + 1.0f, 0.0f);
                float iou = inter / (iar + s_area[jc] - inter);
                unsigned int sup = (iou > NMS_THR && j > i && j < nv) ? 1u : 0u;
                bits |= sup << jj;
            }
        }
        s_sup[task] = bits;
    }
    __syncthreads();

    // ---- Phase D: serial greedy scan, one wave, 10 lanes own keep words ----
    if (tid < 64) {
        const int l  = tid;
        const int lw = (l < NWORDS) ? l : 0;
        const int lo = lw * 32;
        unsigned int rem = (nv >= lo + 32) ? 0xFFFFFFFFu
                         : (nv <= lo ? 0u : ((1u << (nv - lo)) - 1u));
        #pragma unroll 4
        for (int i = 0; i < nv; ++i) {
            unsigned int sv = s_sup[i * NWORDS + lw];            // prefetchable
            unsigned int wsel = (unsigned int)__builtin_amdgcn_readlane((int)rem, i >> 5);
            unsigned int alive = (wsel >> (i & 31)) & 1u;
            rem &= ~(sv & (0u - alive));
        }
        if (l < NWORDS) s_keepw[l] = rem;
    }
    __syncthreads();

    // ---- Phase E: parallel compaction of kept boxes (first KK only) + count ----
    if (tid == 0) {
        int total = 0;
        for (int q = 0; q < NWORDS; ++q) total += __popc(s_keepw[q]);
        wsCount[b * NFG + ci] = total;
    }
    for (int p = tid; p < RR; p += THREADS) {
        const int w = p >> 5, bit = p & 31;
        const unsigned int kw = s_keepw[w];
        if ((kw >> bit) & 1u) {
            int pre = 0;
            for (int q = 0; q < w; ++q) pre += __popc(s_keepw[q]);
            pre += __popc(kw & ((1u << bit) - 1u));
            if (pre < KK) {
                float* dst = wsBoxes + (((size_t)(b * NFG + ci)) * KK + pre) * 4;
                dst[0] = s_sbox[p * 4 + 0];
                dst[1] = s_sbox[p * 4 + 1];
                dst[2] = s_sbox[p * 4 + 2];
                dst[3] = s_sbox[p * 4 + 3];
            }
        }
    }
}

__global__ __launch_bounds__(64)
void select_topk_kernel(const float* __restrict__ wsBoxes,
                        const int*   __restrict__ wsCount,
                        float* __restrict__ out,   // [B,KK,5] then [B] counts
                        int B)
{
    const int b = blockIdx.x;
    const int tid = threadIdx.x;

    __shared__ int s_cnt[NFG];
    __shared__ int s_pref[NFG + 1];
    __shared__ int s_n;

    if (tid < NFG) s_cnt[tid] = wsCount[b * NFG + tid];
    __syncthreads();
    if (tid == 0) {
        int acc = 0, full = 0;
        for (int q = 0; q < NFG; ++q) {
            s_pref[q] = acc;
            int cc = s_cnt[q];
            acc += (cc < KK) ? cc : KK;
            full += cc;
        }
        s_pref[NFG] = acc;
        s_n = (full < KK) ? full : KK;
    }
    __syncthreads();

    const int n = s_n;
    if (tid < KK) {
        float* ob = out + (size_t)b * (KK * 5) + tid * 5;
        if (tid < n) {
            int cc = 0;
            for (int q = 1; q < NFG; ++q) if (s_pref[q] <= tid) cc = q;
            const int slot = tid - s_pref[cc];
            const float* bp = wsBoxes + (((size_t)(b * NFG + cc)) * KK + slot) * 4;
            ob[0] = bp[0];
            ob[1] = bp[1];
            ob[2] = bp[2];
            ob[3] = bp[3];
            ob[4] = (float)(cc + 1);
        } else {
            ob[0] = 0.0f; ob[1] = 0.0f; ob[2] = 0.0f; ob[3] = 0.0f; ob[4] = 0.0f;
        }
    }
    if (tid == 0) out[(size_t)B * KK * 5 + b] = (float)n;
}

extern "C" void kernel_launch(void* const* d_in, const int* in_sizes, int n_in,
                              void* d_out, int out_size, void* d_ws, size_t ws_size,
                              hipStream_t stream)
{
    const float* cls_prob  = (const float*)d_in[0];
    const float* rois      = (const float*)d_in[1];
    const float* bbox_pred = (const float*)d_in[2];
    const float* im_info   = (const float*)d_in[3];
    const float* thr       = (const float*)d_in[4];
    const int B = in_sizes[3] / 3;   // im_info is [B,3]

    float* wsBoxes = (float*)d_ws;                                         // B*NFG*KK*4 floats
    int*   wsCount = (int*)((char*)d_ws + (size_t)B * NFG * KK * 4 * sizeof(float));

    nms_per_class_kernel<<<B * NFG, THREADS, 0, stream>>>(
        cls_prob, rois, bbox_pred, im_info, thr, wsBoxes, wsCount);
    select_topk_kernel<<<B, 64, 0, stream>>>(
        wsBoxes, wsCount, (float*)d_out, B);
}